// Round 1
// baseline (240.217 us; speedup 1.0000x reference)
//
#include <hip/hip_runtime.h>

// Fused deformable-conv network, one block per image.
// Pipeline per image (28x28, 1 ch):
//   offset = conv3x3(x, w_off, pad 1) + b_off          -> 18 x 28 x 28
//   bilinear deform sample (9 taps/pos), conv w_conv    -> 8 x 28 x 28
//   relu -> maxpool 2x2 -> flatten (o,ph,pw) -> FC 1568->10

#define HH 28
#define WW 28
#define HP 30
#define WP 30
#define NPOS (HH * WW)        // 784
#define NPOOL (8 * 14 * 14)   // 1568

__global__ __launch_bounds__(256) void deform_net_kernel(
    const float* __restrict__ x,       // (B,1,28,28)
    const float* __restrict__ w_off,   // (18,1,3,3)
    const float* __restrict__ b_off,   // (18,)
    const float* __restrict__ w_conv,  // (8,1,3,3)
    const float* __restrict__ w_fc,    // (10,1568)
    const float* __restrict__ b_fc,    // (10,)
    float* __restrict__ out)           // (B,10)
{
    __shared__ float xs[HP * WP];        // padded image, 900 floats
    __shared__ float conv_s[8 * NPOS];   // relu'd deform-conv output, 6272 floats
    __shared__ float w_off_s[162];
    __shared__ float b_off_s[18];
    __shared__ float w_conv_s[72];
    __shared__ float red[4][10];

    const int b   = blockIdx.x;
    const int tid = threadIdx.x;

    if (tid < 162) w_off_s[tid]  = w_off[tid];
    if (tid < 18)  b_off_s[tid]  = b_off[tid];
    if (tid < 72)  w_conv_s[tid] = w_conv[tid];

    // Stage zero-padded image into LDS.
    const float* xb = x + (size_t)b * NPOS;
    for (int i = tid; i < HP * WP; i += 256) {
        int r = i / WP, c = i % WP;
        float v = 0.f;
        if (r >= 1 && r <= HH && c >= 1 && c <= WW)
            v = xb[(r - 1) * WW + (c - 1)];
        xs[i] = v;
    }
    __syncthreads();

    // Phase 1: per-position offset conv + bilinear deform sample + 8-ch conv.
    for (int pos = tid; pos < NPOS; pos += 256) {
        const int h = pos / WW, w = pos % WW;

        // 3x3 neighborhood in padded coords (same taps feed the offset conv).
        float nb[9];
        #pragma unroll
        for (int i = 0; i < 3; i++)
            #pragma unroll
            for (int j = 0; j < 3; j++)
                nb[i * 3 + j] = xs[(h + i) * WP + (w + j)];

        // 18 offset channels: ch k = x-offset of tap k, ch k+9 = y-offset.
        float offv[18];
        #pragma unroll
        for (int c = 0; c < 18; c++) {
            float a = b_off_s[c];
            #pragma unroll
            for (int t = 0; t < 9; t++) a = fmaf(w_off_s[c * 9 + t], nb[t], a);
            offv[c] = a;
        }

        float acc[8];
        #pragma unroll
        for (int o = 0; o < 8; o++) acc[o] = 0.f;

        #pragma unroll
        for (int k = 0; k < 9; k++) {
            // p = p0 + pn + offset, in padded coords: p0=(h+1,w+1), pn=(k/3-1,k%3-1)
            float p_x = (float)(h + k / 3) + offv[k];
            float p_y = (float)(w + k % 3) + offv[k + 9];

            float q0x = floorf(p_x), q0y = floorf(p_y);
            float qltx = fminf(fmaxf(q0x,       0.f), 29.f);
            float qlty = fminf(fmaxf(q0y,       0.f), 29.f);
            float qrbx = fminf(fmaxf(q0x + 1.f, 0.f), 29.f);
            float qrby = fminf(fmaxf(q0y + 1.f, 0.f), 29.f);
            float px   = fminf(fmaxf(p_x,       0.f), 29.f);
            float py   = fminf(fmaxf(p_y,       0.f), 29.f);

            float gltx = 1.f + (qltx - px);
            float glty = 1.f + (qlty - py);
            float grbx = 1.f - (qrbx - px);
            float grby = 1.f - (qrby - py);

            int ilx = (int)qltx, ily = (int)qlty;
            int irx = (int)qrbx, iry = (int)qrby;

            float xlt = xs[ilx * WP + ily];
            float xrb = xs[irx * WP + iry];
            float xlb = xs[ilx * WP + iry];
            float xrt = xs[irx * WP + ily];

            float s = gltx * glty * xlt + grbx * grby * xrb
                    + gltx * grby * xlb + grbx * glty * xrt;

            #pragma unroll
            for (int o = 0; o < 8; o++) acc[o] = fmaf(w_conv_s[o * 9 + k], s, acc[o]);
        }

        #pragma unroll
        for (int o = 0; o < 8; o++)
            conv_s[o * NPOS + pos] = fmaxf(acc[o], 0.f);  // relu (commutes w/ maxpool)
    }
    __syncthreads();

    // Phase 2: fused maxpool 2x2 + FC partial sums.
    float fc[10];
    #pragma unroll
    for (int c = 0; c < 10; c++) fc[c] = 0.f;

    for (int j = tid; j < NPOOL; j += 256) {
        int o   = j / 196;
        int rem = j % 196;
        int ph  = rem / 14, pw = rem % 14;
        const float* base = conv_s + o * NPOS + (2 * ph) * WW + 2 * pw;
        float m = fmaxf(fmaxf(base[0], base[1]), fmaxf(base[WW], base[WW + 1]));
        #pragma unroll
        for (int c = 0; c < 10; c++) fc[c] = fmaf(m, w_fc[c * NPOOL + j], fc[c]);
    }

    // Wave (64-lane) shuffle reduce, then cross-wave via LDS.
    #pragma unroll
    for (int c = 0; c < 10; c++) {
        #pragma unroll
        for (int sh = 32; sh > 0; sh >>= 1)
            fc[c] += __shfl_down(fc[c], sh, 64);
    }
    const int wave = tid >> 6, lane = tid & 63;
    if (lane == 0) {
        #pragma unroll
        for (int c = 0; c < 10; c++) red[wave][c] = fc[c];
    }
    __syncthreads();
    if (tid < 10) {
        float r = red[0][tid] + red[1][tid] + red[2][tid] + red[3][tid] + b_fc[tid];
        out[b * 10 + tid] = r;
    }
}

extern "C" void kernel_launch(void* const* d_in, const int* in_sizes, int n_in,
                              void* d_out, int out_size, void* d_ws, size_t ws_size,
                              hipStream_t stream) {
    const float* x      = (const float*)d_in[0];
    const float* w_off  = (const float*)d_in[1];
    const float* b_off  = (const float*)d_in[2];
    const float* w_conv = (const float*)d_in[3];
    const float* w_fc   = (const float*)d_in[4];
    const float* b_fc   = (const float*)d_in[5];
    float* out = (float*)d_out;

    const int B = in_sizes[0] / (HH * WW);
    deform_net_kernel<<<B, 256, 0, stream>>>(x, w_off, b_off, w_conv, w_fc, b_fc, out);
}

// Round 2
// 130.843 us; speedup vs baseline: 1.8359x; 1.8359x over previous
//
#include <hip/hip_runtime.h>

// Fully-fused deformable-conv net. One block (256 thr) per image,
// one thread per 2x2 maxpool cell (196 cells). No intermediate conv map:
// each thread computes 4 deform-conv positions (ILP x4), relu+maxpool in
// registers, FMAs straight into 10 FC accumulators, block-reduces.
// Small weights read via wave-uniform global addresses -> s_load + SGPR FMA.

#define HH 28
#define WW 28
#define HP 30
#define WP 30
#define NPOS (HH * WW)        // 784
#define NPOOL (8 * 14 * 14)   // 1568

__global__ __launch_bounds__(256) void deform_net_kernel(
    const float* __restrict__ x,       // (B,1,28,28)
    const float* __restrict__ w_off,   // (18,1,3,3)
    const float* __restrict__ b_off,   // (18,)
    const float* __restrict__ w_conv,  // (8,1,3,3)
    const float* __restrict__ w_fc,    // (10,1568)
    const float* __restrict__ b_fc,    // (10,)
    float* __restrict__ out)           // (B,10)
{
    __shared__ float xs[HP * WP];  // padded image, 900 floats
    __shared__ float red[4][10];

    const int b   = blockIdx.x;
    const int tid = threadIdx.x;

    // Stage zero-padded image into LDS.
    const float* xb = x + (size_t)b * NPOS;
    for (int i = tid; i < HP * WP; i += 256) {
        int r = i / WP, c = i % WP;
        float v = 0.f;
        if (r >= 1 && r <= HH && c >= 1 && c <= WW)
            v = xb[(r - 1) * WW + (c - 1)];
        xs[i] = v;
    }
    __syncthreads();

    float fc[10];
    #pragma unroll
    for (int c = 0; c < 10; c++) fc[c] = 0.f;

    if (tid < 196) {
        const int ph = tid / 14, pw = tid % 14;   // pool cell coords
        const int h0 = 2 * ph, w0 = 2 * pw;       // top-left output position

        // 4x4 padded-image neighborhood covering all 4 positions' 3x3 taps.
        float nb[16];
        #pragma unroll
        for (int i = 0; i < 4; i++)
            #pragma unroll
            for (int j = 0; j < 4; j++)
                nb[i * 4 + j] = xs[(h0 + i) * WP + (w0 + j)];

        float acc[4][8];
        #pragma unroll
        for (int p = 0; p < 4; p++)
            #pragma unroll
            for (int o = 0; o < 8; o++) acc[p][o] = 0.f;

        #pragma unroll
        for (int k = 0; k < 9; k++) {          // deform tap
            const int kx = k / 3, ky = k % 3;
            #pragma unroll
            for (int p = 0; p < 4; p++) {      // position within pool cell
                const int dh = p >> 1, dw = p & 1;

                // offset channels k (x) and k+9 (y): 3x3 conv at (h0+dh, w0+dw)
                float offx = b_off[k], offy = b_off[k + 9];
                #pragma unroll
                for (int t = 0; t < 9; t++) {
                    float nv = nb[(dh + t / 3) * 4 + (dw + t % 3)];
                    offx = fmaf(w_off[k * 9 + t],        nv, offx);
                    offy = fmaf(w_off[(k + 9) * 9 + t],  nv, offy);
                }

                // sample coords in padded frame: p0=(h+1,w+1), pn=(kx-1,ky-1)
                float p_x = (float)(h0 + dh + kx) + offx;
                float p_y = (float)(w0 + dw + ky) + offy;

                float q0x = floorf(p_x), q0y = floorf(p_y);
                float qltx = fminf(fmaxf(q0x,       0.f), 29.f);
                float qlty = fminf(fmaxf(q0y,       0.f), 29.f);
                float qrbx = fminf(fmaxf(q0x + 1.f, 0.f), 29.f);
                float qrby = fminf(fmaxf(q0y + 1.f, 0.f), 29.f);
                float px   = fminf(fmaxf(p_x,       0.f), 29.f);
                float py   = fminf(fmaxf(p_y,       0.f), 29.f);

                float gltx = 1.f + (qltx - px);
                float glty = 1.f + (qlty - py);
                float grbx = 1.f - (qrbx - px);
                float grby = 1.f - (qrby - py);

                int ilx = (int)qltx, ily = (int)qlty;
                int irx = (int)qrbx, iry = (int)qrby;

                float xlt = xs[ilx * WP + ily];
                float xrb = xs[irx * WP + iry];
                float xlb = xs[ilx * WP + iry];
                float xrt = xs[irx * WP + ily];

                float s = gltx * glty * xlt + grbx * grby * xrb
                        + gltx * grby * xlb + grbx * glty * xrt;

                #pragma unroll
                for (int o = 0; o < 8; o++)
                    acc[p][o] = fmaf(w_conv[o * 9 + k], s, acc[p][o]);
            }
        }

        // relu + 2x2 maxpool in registers, then FC partial sums.
        #pragma unroll
        for (int o = 0; o < 8; o++) {
            float m = fmaxf(fmaxf(acc[0][o], acc[1][o]),
                            fmaxf(acc[2][o], acc[3][o]));
            m = fmaxf(m, 0.f);
            const float* wrow = w_fc + o * 196 + tid;  // flat idx o*196+cell
            #pragma unroll
            for (int c = 0; c < 10; c++)
                fc[c] = fmaf(m, wrow[c * NPOOL], fc[c]);
        }
    }

    // Block reduction: 64-lane shuffle, then cross-wave via LDS.
    #pragma unroll
    for (int c = 0; c < 10; c++) {
        #pragma unroll
        for (int sh = 32; sh > 0; sh >>= 1)
            fc[c] += __shfl_down(fc[c], sh, 64);
    }
    const int wave = tid >> 6, lane = tid & 63;
    if (lane == 0) {
        #pragma unroll
        for (int c = 0; c < 10; c++) red[wave][c] = fc[c];
    }
    __syncthreads();
    if (tid < 10)
        out[b * 10 + tid] = red[0][tid] + red[1][tid] + red[2][tid]
                          + red[3][tid] + b_fc[tid];
}

extern "C" void kernel_launch(void* const* d_in, const int* in_sizes, int n_in,
                              void* d_out, int out_size, void* d_ws, size_t ws_size,
                              hipStream_t stream) {
    const float* x      = (const float*)d_in[0];
    const float* w_off  = (const float*)d_in[1];
    const float* b_off  = (const float*)d_in[2];
    const float* w_conv = (const float*)d_in[3];
    const float* w_fc   = (const float*)d_in[4];
    const float* b_fc   = (const float*)d_in[5];
    float* out = (float*)d_out;

    const int B = in_sizes[0] / NPOS;
    deform_net_kernel<<<B, 256, 0, stream>>>(x, w_off, b_off, w_conv, w_fc, b_fc, out);
}